// Round 4
// baseline (560.052 us; speedup 1.0000x reference)
//
#include <hip/hip_runtime.h>
#include <hip/hip_bf16.h>

#define N_NODES 50000
#define N_EDGES 800000
#define N_TOT   (N_EDGES + N_NODES)   // edges + self loops
#define HEADS   4
#define NEG_SLOPE 0.2f

template <typename T> __device__ __forceinline__ float cvt(T v);
template <> __device__ __forceinline__ float cvt<float>(float v) { return v; }
template <> __device__ __forceinline__ float cvt<__hip_bfloat16>(__hip_bfloat16 v) {
    return __bfloat162float(v);
}

// ---------------- runtime dtype probes (host can't sync under graph capture) -
// flags[0]: edge_index is int64. flags[1]: float inputs are fp32.
__global__ void k_detect(const unsigned* __restrict__ xw, const int* __restrict__ ei,
                         int* __restrict__ flags) {
    if (blockIdx.x == 0 && threadIdx.x == 0) {
        int all0 = 1;
        for (int i = 1; i < 64; i += 2) all0 &= (ei[i] == 0);
        flags[0] = all0;
        int sane = 0;
        for (int i = 0; i < 64; ++i) {
            unsigned e = (xw[i] >> 7) & 0xFF;   // exponent of low half viewed as bf16
            sane += (e >= 90 && e <= 141);
        }
        flags[1] = (sane < 32);                 // junk low halves => fp32 buffer
    }
}

// ---------------- init workspace (ws is poisoned 0xAA before every launch) ---
__global__ __launch_bounds__(256) void k_init(float* __restrict__ s,
                                              float* __restrict__ acc) {
    int i = blockIdx.x * blockDim.x + threadIdx.x;
    if (i < N_NODES * 64) acc[i] = 0.0f;
    if (i < N_NODES * HEADS) s[i] = 0.0f;
}

// ---------------- xt = x @ W (bf16 out), plus a_src/a_dst head dots ----------
// one block (256 thr) per node; thread c computes xt[n, c]; wave w == head w.
// Attention dots use the fp32 accumulator (pre-rounding) for exact logits.
template <typename T>
__device__ __forceinline__ void transform_body(
    const T* __restrict__ x, const T* __restrict__ W,
    const T* __restrict__ att_src, const T* __restrict__ att_dst,
    __hip_bfloat16* __restrict__ xt, float* __restrict__ a_src,
    float* __restrict__ a_dst) {
    __shared__ float xs[64];
    const int n = blockIdx.x;
    const int c = threadIdx.x;
    if (c < 64) xs[c] = cvt<T>(x[n * 64 + c]);
    __syncthreads();
    float acc = 0.0f;
#pragma unroll
    for (int k = 0; k < 64; ++k)
        acc += xs[k] * cvt<T>(W[k * 256 + c]);   // coalesced 256-wide rows; W L1-resident
    xt[(size_t)n * 256 + c] = __float2bfloat16(acc);

    float ps = acc * cvt<T>(att_src[c]);   // att_* is [H,C] flat == index c
    float pd = acc * cvt<T>(att_dst[c]);
#pragma unroll
    for (int off = 32; off > 0; off >>= 1) {
        ps += __shfl_down(ps, off, 64);
        pd += __shfl_down(pd, off, 64);
    }
    if ((c & 63) == 0) {
        int h = c >> 6;
        a_src[n * HEADS + h] = ps;
        a_dst[n * HEADS + h] = pd;
    }
}

__global__ __launch_bounds__(256) void k_transform(
    const void* __restrict__ x, const void* __restrict__ W,
    const void* __restrict__ att_src, const void* __restrict__ att_dst,
    const int* __restrict__ flags,
    __hip_bfloat16* __restrict__ xt, float* __restrict__ a_src,
    float* __restrict__ a_dst) {
    if (flags[1])
        transform_body<float>((const float*)x, (const float*)W,
                              (const float*)att_src, (const float*)att_dst,
                              xt, a_src, a_dst);
    else
        transform_body<__hip_bfloat16>((const __hip_bfloat16*)x, (const __hip_bfloat16*)W,
                                       (const __hip_bfloat16*)att_src,
                                       (const __hip_bfloat16*)att_dst,
                                       xt, a_src, a_dst);
}

__device__ __forceinline__ void edge_endpoints(const int* __restrict__ ei, int t, int f64,
                                               int& src, int& dst) {
    if (t < N_EDGES) {
        if (f64) { src = ei[2 * t]; dst = ei[2 * N_EDGES + 2 * t]; }   // int64 low words
        else     { src = ei[t];     dst = ei[N_EDGES + t]; }           // int32 layout
    } else { src = t - N_EDGES; dst = src; }                           // appended self loops
}

// ---------------- per-edge softmax numerator + denominator -------------------
// One thread per edge; all 4 heads. No max-subtraction: logits ~N(0,1.2),
// max over 3.4M draws ~6 => exp<=500, no overflow; softmax shift-invariant.
__global__ __launch_bounds__(256) void k_edge(const int* __restrict__ ei,
                                              const int* __restrict__ flags,
                                              const float* __restrict__ a_src,
                                              const float* __restrict__ a_dst,
                                              float4* __restrict__ p,
                                              float* __restrict__ s) {
    int t = blockIdx.x * blockDim.x + threadIdx.x;
    if (t >= N_TOT) return;
    int f64 = flags[0];
    int src, dst; edge_endpoints(ei, t, f64, src, dst);
    const float4 as = ((const float4*)a_src)[src];
    const float4 ad = ((const float4*)a_dst)[dst];
    float e0 = as.x + ad.x, e1 = as.y + ad.y, e2 = as.z + ad.z, e3 = as.w + ad.w;
    e0 = e0 > 0.f ? e0 : NEG_SLOPE * e0;  e1 = e1 > 0.f ? e1 : NEG_SLOPE * e1;
    e2 = e2 > 0.f ? e2 : NEG_SLOPE * e2;  e3 = e3 > 0.f ? e3 : NEG_SLOPE * e3;
    float4 pe = make_float4(__expf(e0), __expf(e1), __expf(e2), __expf(e3));
    p[t] = pe;
    float* sd = s + dst * HEADS;
    atomicAdd(sd + 0, pe.x); atomicAdd(sd + 1, pe.y);
    atomicAdd(sd + 2, pe.z); atomicAdd(sd + 3, pe.w);
}

// ---------------- invert denominators ----------------------------------------
__global__ __launch_bounds__(256) void k_inv(float* __restrict__ s) {
    int i = blockIdx.x * blockDim.x + threadIdx.x;
    if (i < N_NODES * HEADS) s[i] = 1.0f / s[i];
}

// ---------------- weighted scatter-aggregate, head-sum fused -----------------
// one wave per edge; lane = channel; softmax already hoisted: ~8 VALU/head.
__global__ __launch_bounds__(256) void k_aggregate(
    const int* __restrict__ ei, const int* __restrict__ flags,
    const float4* __restrict__ p, const float* __restrict__ inv_s,
    const __hip_bfloat16* __restrict__ xt, float* __restrict__ acc) {
    int gid = blockIdx.x * blockDim.x + threadIdx.x;
    int t = gid >> 6;
    int lane = threadIdx.x & 63;
    if (t >= N_TOT) return;
    int f64 = flags[0];
    int src, dst; edge_endpoints(ei, t, f64, src, dst);
    const float4 pe = p[t];                              // broadcast 16B load
    const float4 is = ((const float4*)inv_s)[dst];       // broadcast 16B load
    const __hip_bfloat16* xr = xt + (size_t)src * 256 + lane;
    float v = (pe.x * is.x) * cvt<__hip_bfloat16>(xr[0])
            + (pe.y * is.y) * cvt<__hip_bfloat16>(xr[64])
            + (pe.z * is.z) * cvt<__hip_bfloat16>(xr[128])
            + (pe.w * is.w) * cvt<__hip_bfloat16>(xr[192]);
    atomicAdd(acc + (size_t)dst * 64 + lane, v);
}

// ---------------- mean heads + bias, relu, fc → fp32 scores ------------------
template <typename T>
__device__ __forceinline__ void final_body(const float* __restrict__ acc,
                                           const T* __restrict__ bias,
                                           const T* __restrict__ fc_w,
                                           const T* __restrict__ fc_b,
                                           float* __restrict__ out) {
    int gid = blockIdx.x * blockDim.x + threadIdx.x;
    int n = gid >> 6;
    int lane = threadIdx.x & 63;
    if (n >= N_NODES) return;
    float v = acc[(size_t)n * 64 + lane] * (1.0f / HEADS) + cvt<T>(bias[lane]);
    v = v > 0.0f ? v : 0.0f;          // relu
    v *= cvt<T>(fc_w[lane]);          // fc_w is [64,1]
#pragma unroll
    for (int off = 32; off > 0; off >>= 1) v += __shfl_down(v, off, 64);
    if (lane == 0) out[n] = v + cvt<T>(fc_b[0]);   // fp32 output (reference dtype)
}

__global__ __launch_bounds__(256) void k_final(const float* __restrict__ acc,
                                               const void* __restrict__ bias,
                                               const void* __restrict__ fc_w,
                                               const void* __restrict__ fc_b,
                                               const int* __restrict__ flags,
                                               float* __restrict__ out) {
    if (flags[1])
        final_body<float>(acc, (const float*)bias, (const float*)fc_w,
                          (const float*)fc_b, out);
    else
        final_body<__hip_bfloat16>(acc, (const __hip_bfloat16*)bias,
                                   (const __hip_bfloat16*)fc_w,
                                   (const __hip_bfloat16*)fc_b, out);
}

extern "C" void kernel_launch(void* const* d_in, const int* in_sizes, int n_in,
                              void* d_out, int out_size, void* d_ws, size_t ws_size,
                              hipStream_t stream) {
    const void* x       = d_in[0];
    const int*  ei      = (const int*)d_in[1];
    const void* W       = d_in[2];
    const void* att_src = d_in[3];
    const void* att_dst = d_in[4];
    const void* bias    = d_in[5];
    const void* fc_w    = d_in[6];
    const void* fc_b    = d_in[7];
    float* out = (float*)d_out;

    char* wsb = (char*)d_ws;
    __hip_bfloat16* xt = (__hip_bfloat16*)wsb;                 // N*256 bf16 (25.6 MB)
    float4* p    = (float4*)(wsb + (size_t)N_NODES * 256 * 2); // N_TOT float4 (13.6 MB)
    float* s     = (float*)(p + N_TOT);                        // N*4
    float* a_src = s + N_NODES * HEADS;                        // N*4
    float* a_dst = a_src + N_NODES * HEADS;                    // N*4
    float* acc   = a_dst + N_NODES * HEADS;                    // N*64 (12.8 MB)
    int*   flags = (int*)(acc + (size_t)N_NODES * 64);

    k_detect<<<1, 64, 0, stream>>>((const unsigned*)x, ei, flags);
    k_init<<<(N_NODES * 64 + 255) / 256, 256, 0, stream>>>(s, acc);
    k_transform<<<N_NODES, 256, 0, stream>>>(x, W, att_src, att_dst, flags,
                                             xt, a_src, a_dst);
    k_edge<<<(N_TOT + 255) / 256, 256, 0, stream>>>(ei, flags, a_src, a_dst, p, s);
    k_inv<<<(N_NODES * HEADS + 255) / 256, 256, 0, stream>>>(s);
    k_aggregate<<<((size_t)N_TOT * 64 + 255) / 256, 256, 0, stream>>>(
        ei, flags, p, s, xt, acc);
    k_final<<<(N_NODES * 64 + 255) / 256, 256, 0, stream>>>(acc, bias, fc_w, fc_b,
                                                            flags, out);
}

// Round 5
// 441.512 us; speedup vs baseline: 1.2685x; 1.2685x over previous
//
#include <hip/hip_runtime.h>
#include <hip/hip_bf16.h>

#define N_NODES 50000
#define N_EDGES 800000
#define N_TOT   (N_EDGES + N_NODES)   // edges + appended self loops
#define HEADS   4
#define NEG_SLOPE 0.2f
#define NPB     64                    // nodes per transform block

template <typename T> __device__ __forceinline__ float cvt(T v);
template <> __device__ __forceinline__ float cvt<float>(float v) { return v; }
template <> __device__ __forceinline__ float cvt<__hip_bfloat16>(__hip_bfloat16 v) {
    return __bfloat162float(v);
}
__device__ __forceinline__ float bfbits(unsigned short u) {
    return __uint_as_float(((unsigned)u) << 16);
}

// ---------------- runtime dtype probes (host can't sync under graph capture) -
// flags[0]: edge_index is int64. flags[1]: float inputs are fp32.
__global__ void k_detect(const unsigned* __restrict__ xw, const int* __restrict__ ei,
                         int* __restrict__ flags) {
    if (blockIdx.x == 0 && threadIdx.x == 0) {
        int all0 = 1;
        for (int i = 1; i < 64; i += 2) all0 &= (ei[i] == 0);
        flags[0] = all0;
        int sane = 0;
        for (int i = 0; i < 64; ++i) {
            unsigned e = (xw[i] >> 7) & 0xFF;   // exponent of low half viewed as bf16
            sane += (e >= 90 && e <= 141);
        }
        flags[1] = (sane < 32);                 // junk low halves => fp32 buffer
    }
}

__device__ __forceinline__ void edge_endpoints(const int* __restrict__ ei, int t, int f64,
                                               int& src, int& dst) {
    if (t < N_EDGES) {
        if (f64) { src = ei[2 * t]; dst = ei[2 * N_EDGES + 2 * t]; }   // int64 low words
        else     { src = ei[t];     dst = ei[N_EDGES + t]; }           // int32 layout
    } else { src = t - N_EDGES; dst = src; }                           // appended self loops
}

// ---------------- CSR build: zero, count, scan, scatter ----------------------
__global__ __launch_bounds__(256) void k_zero(int* __restrict__ cnt) {
    int i = blockIdx.x * blockDim.x + threadIdx.x;
    if (i < N_NODES) cnt[i] = 0;
}

__global__ __launch_bounds__(256) void k_count(const int* __restrict__ ei,
                                               const int* __restrict__ flags,
                                               int* __restrict__ cnt) {
    int t = blockIdx.x * blockDim.x + threadIdx.x;
    if (t >= N_TOT) return;
    int src, dst; edge_endpoints(ei, t, flags[0], src, dst);
    atomicAdd(cnt + dst, 1);
}

#define SCAN_T 1024
__global__ __launch_bounds__(SCAN_T) void k_scan(const int* __restrict__ cnt,
                                                 int* __restrict__ row_ptr,
                                                 int* __restrict__ cursor) {
    __shared__ int part[SCAN_T];
    const int tid = threadIdx.x;
    const int CH = (N_NODES + SCAN_T - 1) / SCAN_T;      // 49
    int lo = tid * CH, hi = lo + CH < N_NODES ? lo + CH : N_NODES;
    int sum = 0;
    for (int i = lo; i < hi; ++i) sum += cnt[i];
    part[tid] = sum;
    __syncthreads();
    for (int off = 1; off < SCAN_T; off <<= 1) {          // Hillis-Steele inclusive
        int v = (tid >= off) ? part[tid - off] : 0;
        __syncthreads();
        part[tid] += v;
        __syncthreads();
    }
    int excl = (tid == 0) ? 0 : part[tid - 1];
    for (int i = lo; i < hi; ++i) {
        row_ptr[i] = excl; cursor[i] = excl;
        excl += cnt[i];
    }
    if (tid == SCAN_T - 1) row_ptr[N_NODES] = excl;       // == N_TOT
}

// Per edge: softmax numerator p (4 heads, no max-shift: logits ~N(0,1.2),
// max over 3.4M draws ~6 => exp<=500, no overflow), scattered into CSR slot.
__global__ __launch_bounds__(256) void k_scatter(const int* __restrict__ ei,
                                                 const int* __restrict__ flags,
                                                 const float* __restrict__ a_src,
                                                 const float* __restrict__ a_dst,
                                                 int* __restrict__ cursor,
                                                 int* __restrict__ col,
                                                 float4* __restrict__ p_csr) {
    int t = blockIdx.x * blockDim.x + threadIdx.x;
    if (t >= N_TOT) return;
    int src, dst; edge_endpoints(ei, t, flags[0], src, dst);
    const float4 as = ((const float4*)a_src)[src];
    const float4 ad = ((const float4*)a_dst)[dst];
    float e0 = as.x + ad.x, e1 = as.y + ad.y, e2 = as.z + ad.z, e3 = as.w + ad.w;
    e0 = e0 > 0.f ? e0 : NEG_SLOPE * e0;  e1 = e1 > 0.f ? e1 : NEG_SLOPE * e1;
    e2 = e2 > 0.f ? e2 : NEG_SLOPE * e2;  e3 = e3 > 0.f ? e3 : NEG_SLOPE * e3;
    float4 pe = make_float4(__expf(e0), __expf(e1), __expf(e2), __expf(e3));
    int pos = atomicAdd(cursor + dst, 1);
    col[pos] = src;
    p_csr[pos] = pe;
}

// ---------------- xt = x @ W (bf16, [n][ch][head] layout) + attention dots ---
// W column c lives in 64 VGPRs; 64 nodes staged in LDS per block.
template <typename T>
__device__ __forceinline__ void transform_body(
    const T* __restrict__ x, const T* __restrict__ W,
    const T* __restrict__ att_src, const T* __restrict__ att_dst,
    __hip_bfloat16* __restrict__ xt, float* __restrict__ a_src,
    float* __restrict__ a_dst) {
    __shared__ float xs[NPB][64];
    const int c = threadIdx.x;                 // output column 0..255
    const int node0 = blockIdx.x * NPB;
    float wreg[64];
#pragma unroll
    for (int k = 0; k < 64; ++k) wreg[k] = cvt<T>(W[k * 256 + c]);  // coalesced, 1/block
    for (int i = c; i < NPB * 64; i += 256) {
        int n = i >> 6, ch = i & 63, gn = node0 + n;
        xs[n][ch] = (gn < N_NODES) ? cvt<T>(x[gn * 64 + ch]) : 0.f;
    }
    __syncthreads();
    const float asc = cvt<T>(att_src[c]);      // att_* is [H,C] flat == index c
    const float adc = cvt<T>(att_dst[c]);
    for (int n = 0; n < NPB; ++n) {
        int gn = node0 + n;
        if (gn >= N_NODES) break;              // block-uniform
        float acc = 0.f;
#pragma unroll
        for (int k = 0; k < 64; ++k) acc = fmaf(xs[n][k], wreg[k], acc);
        xt[(size_t)gn * 256 + (c & 63) * 4 + (c >> 6)] = __float2bfloat16(acc);
        float ps = acc * asc, pd = acc * adc;
#pragma unroll
        for (int off = 32; off > 0; off >>= 1) {
            ps += __shfl_down(ps, off, 64);
            pd += __shfl_down(pd, off, 64);
        }
        if ((c & 63) == 0) {
            int h = c >> 6;
            a_src[gn * HEADS + h] = ps;
            a_dst[gn * HEADS + h] = pd;
        }
    }
}

__global__ __launch_bounds__(256) void k_transform(
    const void* __restrict__ x, const void* __restrict__ W,
    const void* __restrict__ att_src, const void* __restrict__ att_dst,
    const int* __restrict__ flags,
    __hip_bfloat16* __restrict__ xt, float* __restrict__ a_src,
    float* __restrict__ a_dst) {
    if (flags[1])
        transform_body<float>((const float*)x, (const float*)W,
                              (const float*)att_src, (const float*)att_dst,
                              xt, a_src, a_dst);
    else
        transform_body<__hip_bfloat16>((const __hip_bfloat16*)x, (const __hip_bfloat16*)W,
                                       (const __hip_bfloat16*)att_src,
                                       (const __hip_bfloat16*)att_dst,
                                       xt, a_src, a_dst);
}

// ---------------- fused CSR aggregate + softmax-div + mean + bias/relu/fc ----
// One wave per dst node; lane = channel. No atomics, no acc array.
template <typename T>
__device__ __forceinline__ void agg_body(const int* __restrict__ row_ptr,
                                         const int* __restrict__ col,
                                         const float4* __restrict__ p_csr,
                                         const __hip_bfloat16* __restrict__ xt,
                                         const T* __restrict__ bias,
                                         const T* __restrict__ fc_w,
                                         const T* __restrict__ fc_b,
                                         float* __restrict__ out) {
    const int wid = (blockIdx.x * blockDim.x + threadIdx.x) >> 6;   // dst node
    const int lane = threadIdx.x & 63;
    if (wid >= N_NODES) return;
    const int lo = row_ptr[wid], hi = row_ptr[wid + 1];             // >=1 (self loop)
    float v0 = 0.f, v1 = 0.f, v2 = 0.f, v3 = 0.f;
    float s0 = 0.f, s1 = 0.f, s2 = 0.f, s3 = 0.f;
    for (int e = lo; e < hi; ++e) {
        const int src = col[e];                 // wave-uniform load
        const float4 pe = p_csr[e];             // wave-uniform 16B load
        const ushort4 xr = *(const ushort4*)(xt + (size_t)src * 256 + lane * 4);
        v0 = fmaf(pe.x, bfbits(xr.x), v0);  s0 += pe.x;
        v1 = fmaf(pe.y, bfbits(xr.y), v1);  s1 += pe.y;
        v2 = fmaf(pe.z, bfbits(xr.z), v2);  s2 += pe.z;
        v3 = fmaf(pe.w, bfbits(xr.w), v3);  s3 += pe.w;
    }
    float o = (v0 / s0 + v1 / s1 + v2 / s2 + v3 / s3) * 0.25f + cvt<T>(bias[lane]);
    o = o > 0.f ? o : 0.f;                      // relu
    o *= cvt<T>(fc_w[lane]);                    // fc_w is [64,1]
#pragma unroll
    for (int off = 32; off > 0; off >>= 1) o += __shfl_down(o, off, 64);
    if (lane == 0) out[wid] = o + cvt<T>(fc_b[0]);   // fp32 output
}

__global__ __launch_bounds__(256) void k_aggregate(const int* __restrict__ row_ptr,
                                                   const int* __restrict__ col,
                                                   const float4* __restrict__ p_csr,
                                                   const __hip_bfloat16* __restrict__ xt,
                                                   const void* __restrict__ bias,
                                                   const void* __restrict__ fc_w,
                                                   const void* __restrict__ fc_b,
                                                   const int* __restrict__ flags,
                                                   float* __restrict__ out) {
    if (flags[1])
        agg_body<float>(row_ptr, col, p_csr, xt, (const float*)bias,
                        (const float*)fc_w, (const float*)fc_b, out);
    else
        agg_body<__hip_bfloat16>(row_ptr, col, p_csr, xt, (const __hip_bfloat16*)bias,
                                 (const __hip_bfloat16*)fc_w,
                                 (const __hip_bfloat16*)fc_b, out);
}

extern "C" void kernel_launch(void* const* d_in, const int* in_sizes, int n_in,
                              void* d_out, int out_size, void* d_ws, size_t ws_size,
                              hipStream_t stream) {
    const void* x       = d_in[0];
    const int*  ei      = (const int*)d_in[1];
    const void* W       = d_in[2];
    const void* att_src = d_in[3];
    const void* att_dst = d_in[4];
    const void* bias    = d_in[5];
    const void* fc_w    = d_in[6];
    const void* fc_b    = d_in[7];
    float* out = (float*)d_out;

    char* wsb = (char*)d_ws;
    __hip_bfloat16* xt = (__hip_bfloat16*)wsb;                   // 25.6 MB
    float4* p_csr  = (float4*)(wsb + (size_t)N_NODES * 512);     // 13.6 MB (16B aligned)
    float*  a_src  = (float*)(p_csr + N_TOT);                    // 800 KB
    float*  a_dst  = a_src + N_NODES * HEADS;                    // 800 KB
    int*    col    = (int*)(a_dst + N_NODES * HEADS);            // 3.4 MB
    int*    cnt    = col + N_TOT;                                // 200 KB
    int*    row_ptr= cnt + N_NODES;                              // 200 KB (+1)
    int*    cursor = row_ptr + N_NODES + 1;                      // 200 KB
    int*    flags  = cursor + N_NODES;

    k_detect<<<1, 64, 0, stream>>>((const unsigned*)x, ei, flags);
    k_zero<<<(N_NODES + 255) / 256, 256, 0, stream>>>(cnt);
    k_count<<<(N_TOT + 255) / 256, 256, 0, stream>>>(ei, flags, cnt);
    k_scan<<<1, SCAN_T, 0, stream>>>(cnt, row_ptr, cursor);
    k_transform<<<(N_NODES + NPB - 1) / NPB, 256, 0, stream>>>(
        x, W, att_src, att_dst, flags, xt, a_src, a_dst);
    k_scatter<<<(N_TOT + 255) / 256, 256, 0, stream>>>(ei, flags, a_src, a_dst,
                                                       cursor, col, p_csr);
    k_aggregate<<<((size_t)N_NODES * 64 + 255) / 256, 256, 0, stream>>>(
        row_ptr, col, p_csr, xt, bias, fc_w, fc_b, flags, out);
}

// Round 6
// 339.292 us; speedup vs baseline: 1.6507x; 1.3013x over previous
//
#include <hip/hip_runtime.h>
#include <hip/hip_bf16.h>

#define N_NODES 50000
#define N_EDGES 800000
#define N_TOT   (N_EDGES + N_NODES)   // edges + appended self loops
#define HEADS   4
#define NEG_SLOPE 0.2f
#define NPB     64                    // nodes per transform block
#define SB      256                   // scan tile
#define NB      ((N_NODES + SB - 1) / SB)   // 196 scan blocks

template <typename T> __device__ __forceinline__ float cvt(T v);
template <> __device__ __forceinline__ float cvt<float>(float v) { return v; }
template <> __device__ __forceinline__ float cvt<__hip_bfloat16>(__hip_bfloat16 v) {
    return __bfloat162float(v);
}
__device__ __forceinline__ float bfbits(unsigned short u) {
    return __uint_as_float(((unsigned)u) << 16);
}

// ------------- fused: zero cnt (all blocks) + dtype probes (block 0) ---------
// flags[0]: edge_index is int64. flags[1]: float inputs are fp32.
__global__ __launch_bounds__(256) void k_init(const unsigned* __restrict__ xw,
                                              const int* __restrict__ ei,
                                              int* __restrict__ cnt,
                                              int* __restrict__ flags) {
    int i = blockIdx.x * blockDim.x + threadIdx.x;
    if (i < N_NODES) cnt[i] = 0;
    if (blockIdx.x == 0 && threadIdx.x == 0) {
        int all0 = 1;
        for (int j = 1; j < 64; j += 2) all0 &= (ei[j] == 0);
        flags[0] = all0;
        int sane = 0;
        for (int j = 0; j < 64; ++j) {
            unsigned e = (xw[j] >> 7) & 0xFF;   // exponent of low half viewed as bf16
            sane += (e >= 90 && e <= 141);
        }
        flags[1] = (sane < 32);                 // junk low halves => fp32 buffer
    }
}

__device__ __forceinline__ void edge_endpoints(const int* __restrict__ ei, int t, int f64,
                                               int& src, int& dst) {
    if (t < N_EDGES) {
        if (f64) { src = ei[2 * t]; dst = ei[2 * N_EDGES + 2 * t]; }   // int64 low words
        else     { src = ei[t];     dst = ei[N_EDGES + t]; }           // int32 layout
    } else { src = t - N_EDGES; dst = src; }                           // appended self loops
}

// ---------------- CSR build ---------------------------------------------------
__global__ __launch_bounds__(256) void k_count(const int* __restrict__ ei,
                                               const int* __restrict__ flags,
                                               int* __restrict__ cnt) {
    int t = blockIdx.x * blockDim.x + threadIdx.x;
    if (t >= N_TOT) return;
    int src, dst; edge_endpoints(ei, t, flags[0], src, dst);
    atomicAdd(cnt + dst, 1);
}

// scan stage 1: per-block reduce of cnt -> blksum[NB]
__global__ __launch_bounds__(SB) void k_scan1(const int* __restrict__ cnt,
                                              int* __restrict__ blksum) {
    __shared__ int ws[SB / 64];
    int i = blockIdx.x * SB + threadIdx.x;
    int v = (i < N_NODES) ? cnt[i] : 0;
#pragma unroll
    for (int off = 32; off > 0; off >>= 1) v += __shfl_down(v, off, 64);
    if ((threadIdx.x & 63) == 0) ws[threadIdx.x >> 6] = v;
    __syncthreads();
    if (threadIdx.x == 0)
        blksum[blockIdx.x] = ws[0] + ws[1] + ws[2] + ws[3];
}

// scan stage 2: single block scans NB partials -> exclusive blkoff[NB]
__global__ __launch_bounds__(SB) void k_scan2(const int* __restrict__ blksum,
                                              int* __restrict__ blkoff) {
    __shared__ int sh[SB];
    int t = threadIdx.x;
    sh[t] = (t < NB) ? blksum[t] : 0;
    __syncthreads();
#pragma unroll
    for (int off = 1; off < SB; off <<= 1) {    // Hillis-Steele inclusive
        int v = (t >= off) ? sh[t - off] : 0;
        __syncthreads();
        sh[t] += v;
        __syncthreads();
    }
    if (t < NB) blkoff[t] = (t == 0) ? 0 : sh[t - 1];
}

// scan stage 3: block-local exclusive scan + blkoff -> row_ptr, cursor
__global__ __launch_bounds__(SB) void k_scan3(const int* __restrict__ cnt,
                                              const int* __restrict__ blkoff,
                                              int* __restrict__ row_ptr,
                                              int* __restrict__ cursor) {
    __shared__ int sh[SB];
    int t = threadIdx.x;
    int i = blockIdx.x * SB + t;
    int c = (i < N_NODES) ? cnt[i] : 0;
    sh[t] = c;
    __syncthreads();
#pragma unroll
    for (int off = 1; off < SB; off <<= 1) {    // inclusive scan of this tile
        int v = (t >= off) ? sh[t - off] : 0;
        __syncthreads();
        sh[t] += v;
        __syncthreads();
    }
    if (i < N_NODES) {
        int r = blkoff[blockIdx.x] + sh[t] - c;  // exclusive
        row_ptr[i] = r;
        cursor[i]  = r;
    }
    if (blockIdx.x == 0 && t == 0) row_ptr[N_NODES] = N_TOT;  // total is constant
}

// Per edge: softmax numerator p (4 heads, no max-shift: logits ~N(0,1.2),
// max over 3.4M draws ~6 => exp<=500, no overflow), scattered into CSR slot.
__global__ __launch_bounds__(256) void k_scatter(const int* __restrict__ ei,
                                                 const int* __restrict__ flags,
                                                 const float* __restrict__ a_src,
                                                 const float* __restrict__ a_dst,
                                                 int* __restrict__ cursor,
                                                 int* __restrict__ col,
                                                 float4* __restrict__ p_csr) {
    int t = blockIdx.x * blockDim.x + threadIdx.x;
    if (t >= N_TOT) return;
    int src, dst; edge_endpoints(ei, t, flags[0], src, dst);
    const float4 as = ((const float4*)a_src)[src];
    const float4 ad = ((const float4*)a_dst)[dst];
    float e0 = as.x + ad.x, e1 = as.y + ad.y, e2 = as.z + ad.z, e3 = as.w + ad.w;
    e0 = e0 > 0.f ? e0 : NEG_SLOPE * e0;  e1 = e1 > 0.f ? e1 : NEG_SLOPE * e1;
    e2 = e2 > 0.f ? e2 : NEG_SLOPE * e2;  e3 = e3 > 0.f ? e3 : NEG_SLOPE * e3;
    float4 pe = make_float4(__expf(e0), __expf(e1), __expf(e2), __expf(e3));
    int pos = atomicAdd(cursor + dst, 1);
    col[pos] = src;
    p_csr[pos] = pe;
}

// ---------------- xt = x @ W (bf16, [n][ch][head] layout) + attention dots ---
// W column c lives in 64 VGPRs; 64 nodes staged in LDS per block.
template <typename T>
__device__ __forceinline__ void transform_body(
    const T* __restrict__ x, const T* __restrict__ W,
    const T* __restrict__ att_src, const T* __restrict__ att_dst,
    __hip_bfloat16* __restrict__ xt, float* __restrict__ a_src,
    float* __restrict__ a_dst) {
    __shared__ float xs[NPB][64];
    const int c = threadIdx.x;                 // output column 0..255
    const int node0 = blockIdx.x * NPB;
    float wreg[64];
#pragma unroll
    for (int k = 0; k < 64; ++k) wreg[k] = cvt<T>(W[k * 256 + c]);  // coalesced, 1/block
    for (int i = c; i < NPB * 64; i += 256) {
        int n = i >> 6, ch = i & 63, gn = node0 + n;
        xs[n][ch] = (gn < N_NODES) ? cvt<T>(x[gn * 64 + ch]) : 0.f;
    }
    __syncthreads();
    const float asc = cvt<T>(att_src[c]);      // att_* is [H,C] flat == index c
    const float adc = cvt<T>(att_dst[c]);
    for (int n = 0; n < NPB; ++n) {
        int gn = node0 + n;
        if (gn >= N_NODES) break;              // block-uniform
        float acc = 0.f;
#pragma unroll
        for (int k = 0; k < 64; ++k) acc = fmaf(xs[n][k], wreg[k], acc);
        xt[(size_t)gn * 256 + (c & 63) * 4 + (c >> 6)] = __float2bfloat16(acc);
        float ps = acc * asc, pd = acc * adc;
#pragma unroll
        for (int off = 32; off > 0; off >>= 1) {
            ps += __shfl_down(ps, off, 64);
            pd += __shfl_down(pd, off, 64);
        }
        if ((c & 63) == 0) {
            int h = c >> 6;
            a_src[gn * HEADS + h] = ps;
            a_dst[gn * HEADS + h] = pd;
        }
    }
}

__global__ __launch_bounds__(256) void k_transform(
    const void* __restrict__ x, const void* __restrict__ W,
    const void* __restrict__ att_src, const void* __restrict__ att_dst,
    const int* __restrict__ flags,
    __hip_bfloat16* __restrict__ xt, float* __restrict__ a_src,
    float* __restrict__ a_dst) {
    if (flags[1])
        transform_body<float>((const float*)x, (const float*)W,
                              (const float*)att_src, (const float*)att_dst,
                              xt, a_src, a_dst);
    else
        transform_body<__hip_bfloat16>((const __hip_bfloat16*)x, (const __hip_bfloat16*)W,
                                       (const __hip_bfloat16*)att_src,
                                       (const __hip_bfloat16*)att_dst,
                                       xt, a_src, a_dst);
}

// ---------------- fused CSR aggregate + softmax-div + mean + bias/relu/fc ----
// One wave per dst node; lane = channel. No atomics, no acc array.
template <typename T>
__device__ __forceinline__ void agg_body(const int* __restrict__ row_ptr,
                                         const int* __restrict__ col,
                                         const float4* __restrict__ p_csr,
                                         const __hip_bfloat16* __restrict__ xt,
                                         const T* __restrict__ bias,
                                         const T* __restrict__ fc_w,
                                         const T* __restrict__ fc_b,
                                         float* __restrict__ out) {
    const int wid = (blockIdx.x * blockDim.x + threadIdx.x) >> 6;   // dst node
    const int lane = threadIdx.x & 63;
    if (wid >= N_NODES) return;
    const int lo = row_ptr[wid], hi = row_ptr[wid + 1];             // >=1 (self loop)
    float v0 = 0.f, v1 = 0.f, v2 = 0.f, v3 = 0.f;
    float s0 = 0.f, s1 = 0.f, s2 = 0.f, s3 = 0.f;
    for (int e = lo; e < hi; ++e) {
        const int src = col[e];                 // wave-uniform load
        const float4 pe = p_csr[e];             // wave-uniform 16B load
        const ushort4 xr = *(const ushort4*)(xt + (size_t)src * 256 + lane * 4);
        v0 = fmaf(pe.x, bfbits(xr.x), v0);  s0 += pe.x;
        v1 = fmaf(pe.y, bfbits(xr.y), v1);  s1 += pe.y;
        v2 = fmaf(pe.z, bfbits(xr.z), v2);  s2 += pe.z;
        v3 = fmaf(pe.w, bfbits(xr.w), v3);  s3 += pe.w;
    }
    float o = (v0 / s0 + v1 / s1 + v2 / s2 + v3 / s3) * 0.25f + cvt<T>(bias[lane]);
    o = o > 0.f ? o : 0.f;                      // relu
    o *= cvt<T>(fc_w[lane]);                    // fc_w is [64,1]
#pragma unroll
    for (int off = 32; off > 0; off >>= 1) o += __shfl_down(o, off, 64);
    if (lane == 0) out[wid] = o + cvt<T>(fc_b[0]);   // fp32 output
}

__global__ __launch_bounds__(256) void k_aggregate(const int* __restrict__ row_ptr,
                                                   const int* __restrict__ col,
                                                   const float4* __restrict__ p_csr,
                                                   const __hip_bfloat16* __restrict__ xt,
                                                   const void* __restrict__ bias,
                                                   const void* __restrict__ fc_w,
                                                   const void* __restrict__ fc_b,
                                                   const int* __restrict__ flags,
                                                   float* __restrict__ out) {
    if (flags[1])
        agg_body<float>(row_ptr, col, p_csr, xt, (const float*)bias,
                        (const float*)fc_w, (const float*)fc_b, out);
    else
        agg_body<__hip_bfloat16>(row_ptr, col, p_csr, xt, (const __hip_bfloat16*)bias,
                                 (const __hip_bfloat16*)fc_w,
                                 (const __hip_bfloat16*)fc_b, out);
}

extern "C" void kernel_launch(void* const* d_in, const int* in_sizes, int n_in,
                              void* d_out, int out_size, void* d_ws, size_t ws_size,
                              hipStream_t stream) {
    const void* x       = d_in[0];
    const int*  ei      = (const int*)d_in[1];
    const void* W       = d_in[2];
    const void* att_src = d_in[3];
    const void* att_dst = d_in[4];
    const void* bias    = d_in[5];
    const void* fc_w    = d_in[6];
    const void* fc_b    = d_in[7];
    float* out = (float*)d_out;

    char* wsb = (char*)d_ws;
    __hip_bfloat16* xt = (__hip_bfloat16*)wsb;                   // 25.6 MB
    float4* p_csr  = (float4*)(wsb + (size_t)N_NODES * 512);     // 13.6 MB (16B aligned)
    float*  a_src  = (float*)(p_csr + N_TOT);                    // 800 KB
    float*  a_dst  = a_src + N_NODES * HEADS;                    // 800 KB
    int*    col    = (int*)(a_dst + N_NODES * HEADS);            // 3.4 MB
    int*    cnt    = col + N_TOT;                                // 200 KB
    int*    row_ptr= cnt + N_NODES;                              // 200 KB (+1)
    int*    cursor = row_ptr + N_NODES + 1;                      // 200 KB
    int*    blksum = cursor + N_NODES;                           // NB
    int*    blkoff = blksum + NB;                                // NB
    int*    flags  = blkoff + NB;

    k_init<<<NB, 256, 0, stream>>>((const unsigned*)x, ei, cnt, flags);
    k_count<<<(N_TOT + 255) / 256, 256, 0, stream>>>(ei, flags, cnt);
    k_scan1<<<NB, SB, 0, stream>>>(cnt, blksum);
    k_scan2<<<1, SB, 0, stream>>>(blksum, blkoff);
    k_scan3<<<NB, SB, 0, stream>>>(cnt, blkoff, row_ptr, cursor);
    k_transform<<<(N_NODES + NPB - 1) / NPB, 256, 0, stream>>>(
        x, W, att_src, att_dst, flags, xt, a_src, a_dst);
    k_scatter<<<(N_TOT + 255) / 256, 256, 0, stream>>>(ei, flags, a_src, a_dst,
                                                       cursor, col, p_csr);
    k_aggregate<<<((size_t)N_NODES * 64 + 255) / 256, 256, 0, stream>>>(
        row_ptr, col, p_csr, xt, bias, fc_w, fc_b, flags, out);
}

// Round 7
// 314.661 us; speedup vs baseline: 1.7799x; 1.0783x over previous
//
#include <hip/hip_runtime.h>
#include <hip/hip_bf16.h>

#define N_NODES 50000
#define N_EDGES 800000
#define N_TOT   (N_EDGES + N_NODES)   // edges + appended self loops
#define HEADS   4
#define NEG_SLOPE 0.2f
#define NPB     64                    // nodes per transform block
#define SB      256                   // scan tile
#define NB      ((N_NODES + SB - 1) / SB)   // 196 scan blocks

template <typename T> __device__ __forceinline__ float cvt(T v);
template <> __device__ __forceinline__ float cvt<float>(float v) { return v; }
template <> __device__ __forceinline__ float cvt<__hip_bfloat16>(__hip_bfloat16 v) {
    return __bfloat162float(v);
}
__device__ __forceinline__ float bfbits(unsigned short u) {
    return __uint_as_float(((unsigned)u) << 16);
}

// ------------- fused: zero cnt (all blocks) + dtype probes (block 0) ---------
// flags[0]: edge_index is int64. flags[1]: float inputs are fp32.
__global__ __launch_bounds__(256) void k_init(const unsigned* __restrict__ xw,
                                              const int* __restrict__ ei,
                                              int* __restrict__ cnt,
                                              int* __restrict__ flags) {
    int i = blockIdx.x * blockDim.x + threadIdx.x;
    if (i < N_NODES) cnt[i] = 0;
    if (blockIdx.x == 0 && threadIdx.x == 0) {
        int all0 = 1;
        for (int j = 1; j < 64; j += 2) all0 &= (ei[j] == 0);
        flags[0] = all0;
        int sane = 0;
        for (int j = 0; j < 64; ++j) {
            unsigned e = (xw[j] >> 7) & 0xFF;   // exponent of low half viewed as bf16
            sane += (e >= 90 && e <= 141);
        }
        flags[1] = (sane < 32);                 // junk low halves => fp32 buffer
    }
}

__device__ __forceinline__ void edge_endpoints(const int* __restrict__ ei, int t, int f64,
                                               int& src, int& dst) {
    if (t < N_EDGES) {
        if (f64) { src = ei[2 * t]; dst = ei[2 * N_EDGES + 2 * t]; }   // int64 low words
        else     { src = ei[t];     dst = ei[N_EDGES + t]; }           // int32 layout
    } else { src = t - N_EDGES; dst = src; }                           // appended self loops
}

__device__ __forceinline__ int edge_dst(const int* __restrict__ ei, int t, int f64) {
    if (t < N_EDGES) return f64 ? ei[2 * N_EDGES + 2 * t] : ei[N_EDGES + t];
    return t - N_EDGES;
}

// ---------------- CSR build ---------------------------------------------------
__global__ __launch_bounds__(256) void k_count(const int* __restrict__ ei,
                                               const int* __restrict__ flags,
                                               int* __restrict__ cnt) {
    int t = blockIdx.x * blockDim.x + threadIdx.x;
    if (t >= N_TOT) return;
    atomicAdd(cnt + edge_dst(ei, t, flags[0]), 1);
}

// scan stage 1: per-block reduce of cnt -> blksum[NB]
__global__ __launch_bounds__(SB) void k_scan1(const int* __restrict__ cnt,
                                              int* __restrict__ blksum) {
    __shared__ int ws[SB / 64];
    int i = blockIdx.x * SB + threadIdx.x;
    int v = (i < N_NODES) ? cnt[i] : 0;
#pragma unroll
    for (int off = 32; off > 0; off >>= 1) v += __shfl_down(v, off, 64);
    if ((threadIdx.x & 63) == 0) ws[threadIdx.x >> 6] = v;
    __syncthreads();
    if (threadIdx.x == 0)
        blksum[blockIdx.x] = ws[0] + ws[1] + ws[2] + ws[3];
}

// scan stage 2: single block scans NB partials -> exclusive blkoff[NB]
__global__ __launch_bounds__(SB) void k_scan2(const int* __restrict__ blksum,
                                              int* __restrict__ blkoff) {
    __shared__ int sh[SB];
    int t = threadIdx.x;
    sh[t] = (t < NB) ? blksum[t] : 0;
    __syncthreads();
#pragma unroll
    for (int off = 1; off < SB; off <<= 1) {    // Hillis-Steele inclusive
        int v = (t >= off) ? sh[t - off] : 0;
        __syncthreads();
        sh[t] += v;
        __syncthreads();
    }
    if (t < NB) blkoff[t] = (t == 0) ? 0 : sh[t - 1];
}

// scan stage 3: block-local exclusive scan + blkoff -> row_ptr, cursor
__global__ __launch_bounds__(SB) void k_scan3(const int* __restrict__ cnt,
                                              const int* __restrict__ blkoff,
                                              int* __restrict__ row_ptr,
                                              int* __restrict__ cursor) {
    __shared__ int sh[SB];
    int t = threadIdx.x;
    int i = blockIdx.x * SB + t;
    int c = (i < N_NODES) ? cnt[i] : 0;
    sh[t] = c;
    __syncthreads();
#pragma unroll
    for (int off = 1; off < SB; off <<= 1) {    // inclusive scan of this tile
        int v = (t >= off) ? sh[t - off] : 0;
        __syncthreads();
        sh[t] += v;
        __syncthreads();
    }
    if (i < N_NODES) {
        int r = blkoff[blockIdx.x] + sh[t] - c;  // exclusive
        row_ptr[i] = r;
        cursor[i]  = r;
    }
    if (blockIdx.x == 0 && t == 0) row_ptr[N_NODES] = N_TOT;  // total is constant
}

// slim scatter: CSR column indices only (attention now computed in aggregate)
__global__ __launch_bounds__(256) void k_scatter(const int* __restrict__ ei,
                                                 const int* __restrict__ flags,
                                                 int* __restrict__ cursor,
                                                 int* __restrict__ col) {
    int t = blockIdx.x * blockDim.x + threadIdx.x;
    if (t >= N_TOT) return;
    int src, dst; edge_endpoints(ei, t, flags[0], src, dst);
    int pos = atomicAdd(cursor + dst, 1);
    col[pos] = src;
}

// ---------------- xt = x @ W (bf16, [n][ch][head] layout) + attention dots ---
// W column c lives in 64 VGPRs; 64 nodes staged in LDS per block.
template <typename T>
__device__ __forceinline__ void transform_body(
    const T* __restrict__ x, const T* __restrict__ W,
    const T* __restrict__ att_src, const T* __restrict__ att_dst,
    __hip_bfloat16* __restrict__ xt, float* __restrict__ a_src,
    float* __restrict__ a_dst) {
    __shared__ float xs[NPB][64];
    const int c = threadIdx.x;                 // output column 0..255
    const int node0 = blockIdx.x * NPB;
    float wreg[64];
#pragma unroll
    for (int k = 0; k < 64; ++k) wreg[k] = cvt<T>(W[k * 256 + c]);  // coalesced, 1/block
    for (int i = c; i < NPB * 64; i += 256) {
        int n = i >> 6, ch = i & 63, gn = node0 + n;
        xs[n][ch] = (gn < N_NODES) ? cvt<T>(x[gn * 64 + ch]) : 0.f;
    }
    __syncthreads();
    const float asc = cvt<T>(att_src[c]);      // att_* is [H,C] flat == index c
    const float adc = cvt<T>(att_dst[c]);
    for (int n = 0; n < NPB; ++n) {
        int gn = node0 + n;
        if (gn >= N_NODES) break;              // block-uniform
        float acc = 0.f;
#pragma unroll
        for (int k = 0; k < 64; ++k) acc = fmaf(xs[n][k], wreg[k], acc);
        xt[(size_t)gn * 256 + (c & 63) * 4 + (c >> 6)] = __float2bfloat16(acc);
        float ps = acc * asc, pd = acc * adc;
#pragma unroll
        for (int off = 32; off > 0; off >>= 1) {
            ps += __shfl_down(ps, off, 64);
            pd += __shfl_down(pd, off, 64);
        }
        if ((c & 63) == 0) {
            int h = c >> 6;
            a_src[gn * HEADS + h] = ps;
            a_dst[gn * HEADS + h] = pd;
        }
    }
}

__global__ __launch_bounds__(256) void k_transform(
    const void* __restrict__ x, const void* __restrict__ W,
    const void* __restrict__ att_src, const void* __restrict__ att_dst,
    const int* __restrict__ flags,
    __hip_bfloat16* __restrict__ xt, float* __restrict__ a_src,
    float* __restrict__ a_dst) {
    if (flags[1])
        transform_body<float>((const float*)x, (const float*)W,
                              (const float*)att_src, (const float*)att_dst,
                              xt, a_src, a_dst);
    else
        transform_body<__hip_bfloat16>((const __hip_bfloat16*)x, (const __hip_bfloat16*)W,
                                       (const __hip_bfloat16*)att_src,
                                       (const __hip_bfloat16*)att_dst,
                                       xt, a_src, a_dst);
}

// ---------------- fused aggregate: softmax + weighted sum + mean/bias/relu/fc
// One wave per dst node; lane = channel. Edge metadata processed in chunks of
// 64: lane i computes edge (base+i)'s exp lane-parallel (a_src is L2-resident,
// 800 KB); inner loop unrolled x4 so 4 independent 512 B xt gathers are in
// flight (latency hiding). Denominators accumulate lane-parallel, one
// butterfly reduce per row.
template <typename T>
__device__ __forceinline__ void agg_body(const int* __restrict__ row_ptr,
                                         const int* __restrict__ col,
                                         const float* __restrict__ a_src,
                                         const float* __restrict__ a_dst,
                                         const __hip_bfloat16* __restrict__ xt,
                                         const T* __restrict__ bias,
                                         const T* __restrict__ fc_w,
                                         const T* __restrict__ fc_b,
                                         float* __restrict__ out) {
    const int wid = (blockIdx.x * blockDim.x + threadIdx.x) >> 6;   // dst node
    const int lane = threadIdx.x & 63;
    if (wid >= N_NODES) return;
    const int lo = row_ptr[wid], hi = row_ptr[wid + 1];             // >=1 (self loop)
    const float4 ad = ((const float4*)a_dst)[wid];                  // uniform
    float v0 = 0.f, v1 = 0.f, v2 = 0.f, v3 = 0.f;
    float sp0 = 0.f, sp1 = 0.f, sp2 = 0.f, sp3 = 0.f;               // lane-parallel denom
    for (int base = lo; base < hi; base += 64) {
        int n = hi - base; n = n > 64 ? 64 : n;
        int mycol = 0;
        float4 pe = make_float4(0.f, 0.f, 0.f, 0.f);
        if (lane < n) {
            mycol = col[base + lane];                               // coalesced
            const float4 as = ((const float4*)a_src)[mycol];        // L2-resident gather
            float e0 = as.x + ad.x, e1 = as.y + ad.y;
            float e2 = as.z + ad.z, e3 = as.w + ad.w;
            e0 = e0 > 0.f ? e0 : NEG_SLOPE * e0;  e1 = e1 > 0.f ? e1 : NEG_SLOPE * e1;
            e2 = e2 > 0.f ? e2 : NEG_SLOPE * e2;  e3 = e3 > 0.f ? e3 : NEG_SLOPE * e3;
            pe = make_float4(__expf(e0), __expf(e1), __expf(e2), __expf(e3));
            sp0 += pe.x; sp1 += pe.y; sp2 += pe.z; sp3 += pe.w;
        }
        int j = 0;
        for (; j + 4 <= n; j += 4) {
            int s0 = __shfl(mycol, j, 64),     s1 = __shfl(mycol, j + 1, 64);
            int s2 = __shfl(mycol, j + 2, 64), s3 = __shfl(mycol, j + 3, 64);
            const ushort4 xA = *(const ushort4*)(xt + (size_t)s0 * 256 + lane * 4);
            const ushort4 xB = *(const ushort4*)(xt + (size_t)s1 * 256 + lane * 4);
            const ushort4 xC = *(const ushort4*)(xt + (size_t)s2 * 256 + lane * 4);
            const ushort4 xD = *(const ushort4*)(xt + (size_t)s3 * 256 + lane * 4);
            float a0 = __shfl(pe.x, j, 64), a1 = __shfl(pe.y, j, 64);
            float a2 = __shfl(pe.z, j, 64), a3 = __shfl(pe.w, j, 64);
            v0 = fmaf(a0, bfbits(xA.x), v0); v1 = fmaf(a1, bfbits(xA.y), v1);
            v2 = fmaf(a2, bfbits(xA.z), v2); v3 = fmaf(a3, bfbits(xA.w), v3);
            float b0 = __shfl(pe.x, j + 1, 64), b1 = __shfl(pe.y, j + 1, 64);
            float b2 = __shfl(pe.z, j + 1, 64), b3 = __shfl(pe.w, j + 1, 64);
            v0 = fmaf(b0, bfbits(xB.x), v0); v1 = fmaf(b1, bfbits(xB.y), v1);
            v2 = fmaf(b2, bfbits(xB.z), v2); v3 = fmaf(b3, bfbits(xB.w), v3);
            float c0 = __shfl(pe.x, j + 2, 64), c1 = __shfl(pe.y, j + 2, 64);
            float c2 = __shfl(pe.z, j + 2, 64), c3 = __shfl(pe.w, j + 2, 64);
            v0 = fmaf(c0, bfbits(xC.x), v0); v1 = fmaf(c1, bfbits(xC.y), v1);
            v2 = fmaf(c2, bfbits(xC.z), v2); v3 = fmaf(c3, bfbits(xC.w), v3);
            float d0 = __shfl(pe.x, j + 3, 64), d1 = __shfl(pe.y, j + 3, 64);
            float d2 = __shfl(pe.z, j + 3, 64), d3 = __shfl(pe.w, j + 3, 64);
            v0 = fmaf(d0, bfbits(xD.x), v0); v1 = fmaf(d1, bfbits(xD.y), v1);
            v2 = fmaf(d2, bfbits(xD.z), v2); v3 = fmaf(d3, bfbits(xD.w), v3);
        }
        for (; j < n; ++j) {
            int s0 = __shfl(mycol, j, 64);
            const ushort4 xA = *(const ushort4*)(xt + (size_t)s0 * 256 + lane * 4);
            float a0 = __shfl(pe.x, j, 64), a1 = __shfl(pe.y, j, 64);
            float a2 = __shfl(pe.z, j, 64), a3 = __shfl(pe.w, j, 64);
            v0 = fmaf(a0, bfbits(xA.x), v0); v1 = fmaf(a1, bfbits(xA.y), v1);
            v2 = fmaf(a2, bfbits(xA.z), v2); v3 = fmaf(a3, bfbits(xA.w), v3);
        }
    }
    // butterfly: total denominators in all lanes
#pragma unroll
    for (int msk = 1; msk < 64; msk <<= 1) {
        sp0 += __shfl_xor(sp0, msk, 64); sp1 += __shfl_xor(sp1, msk, 64);
        sp2 += __shfl_xor(sp2, msk, 64); sp3 += __shfl_xor(sp3, msk, 64);
    }
    float o = (v0 / sp0 + v1 / sp1 + v2 / sp2 + v3 / sp3) * 0.25f + cvt<T>(bias[lane]);
    o = o > 0.f ? o : 0.f;                      // relu
    o *= cvt<T>(fc_w[lane]);                    // fc_w is [64,1]
#pragma unroll
    for (int off = 32; off > 0; off >>= 1) o += __shfl_down(o, off, 64);
    if (lane == 0) out[wid] = o + cvt<T>(fc_b[0]);   // fp32 output
}

__global__ __launch_bounds__(256) void k_aggregate(const int* __restrict__ row_ptr,
                                                   const int* __restrict__ col,
                                                   const float* __restrict__ a_src,
                                                   const float* __restrict__ a_dst,
                                                   const __hip_bfloat16* __restrict__ xt,
                                                   const void* __restrict__ bias,
                                                   const void* __restrict__ fc_w,
                                                   const void* __restrict__ fc_b,
                                                   const int* __restrict__ flags,
                                                   float* __restrict__ out) {
    if (flags[1])
        agg_body<float>(row_ptr, col, a_src, a_dst, xt, (const float*)bias,
                        (const float*)fc_w, (const float*)fc_b, out);
    else
        agg_body<__hip_bfloat16>(row_ptr, col, a_src, a_dst, xt,
                                 (const __hip_bfloat16*)bias,
                                 (const __hip_bfloat16*)fc_w,
                                 (const __hip_bfloat16*)fc_b, out);
}

extern "C" void kernel_launch(void* const* d_in, const int* in_sizes, int n_in,
                              void* d_out, int out_size, void* d_ws, size_t ws_size,
                              hipStream_t stream) {
    const void* x       = d_in[0];
    const int*  ei      = (const int*)d_in[1];
    const void* W       = d_in[2];
    const void* att_src = d_in[3];
    const void* att_dst = d_in[4];
    const void* bias    = d_in[5];
    const void* fc_w    = d_in[6];
    const void* fc_b    = d_in[7];
    float* out = (float*)d_out;

    char* wsb = (char*)d_ws;
    __hip_bfloat16* xt = (__hip_bfloat16*)wsb;                   // 25.6 MB
    float*  a_src  = (float*)(wsb + (size_t)N_NODES * 512);      // 800 KB (16B aligned)
    float*  a_dst  = a_src + N_NODES * HEADS;                    // 800 KB
    int*    col    = (int*)(a_dst + N_NODES * HEADS);            // 3.4 MB
    int*    cnt    = col + N_TOT;                                // 200 KB
    int*    row_ptr= cnt + N_NODES;                              // 200 KB (+1)
    int*    cursor = row_ptr + N_NODES + 1;                      // 200 KB
    int*    blksum = cursor + N_NODES;                           // NB
    int*    blkoff = blksum + NB;                                // NB
    int*    flags  = blkoff + NB;

    k_init<<<NB, 256, 0, stream>>>((const unsigned*)x, ei, cnt, flags);
    k_count<<<(N_TOT + 255) / 256, 256, 0, stream>>>(ei, flags, cnt);
    k_scan1<<<NB, SB, 0, stream>>>(cnt, blksum);
    k_scan2<<<1, SB, 0, stream>>>(blksum, blkoff);
    k_scan3<<<NB, SB, 0, stream>>>(cnt, blkoff, row_ptr, cursor);
    k_transform<<<(N_NODES + NPB - 1) / NPB, 256, 0, stream>>>(
        x, W, att_src, att_dst, flags, xt, a_src, a_dst);
    k_scatter<<<(N_TOT + 255) / 256, 256, 0, stream>>>(ei, flags, cursor, col);
    k_aggregate<<<((size_t)N_NODES * 64 + 255) / 256, 256, 0, stream>>>(
        row_ptr, col, a_src, a_dst, xt, bias, fc_w, fc_b, flags, out);
}